// Round 5
// baseline (377.714 us; speedup 1.0000x reference)
//
#include <hip/hip_runtime.h>
#include <hip/hip_bf16.h>

// Problem constants (B=4, S=2048, D=1024, H=16, DK=64)
#define BB 4
#define SS 2048
#define DD 1024
#define HH 16
#define DKK 64

typedef __bf16 bf16x8 __attribute__((ext_vector_type(8)));
typedef float floatx4 __attribute__((ext_vector_type(4)));

#if __has_builtin(__builtin_amdgcn_exp2f)
#define EXP2(x) __builtin_amdgcn_exp2f(x)
#else
#define EXP2(x) exp2f(x)
#endif

__device__ __forceinline__ float b2f(unsigned short u) {
    union { unsigned int i; float f; } c;
    c.i = ((unsigned int)u) << 16;
    return c.f;
}
__device__ __forceinline__ unsigned short f2b(float f) {
    unsigned int i = __float_as_uint(f);
    unsigned int r = (i + 0x7FFFu + ((i >> 16) & 1u)) >> 16;  // RNE
    return (unsigned short)r;
}

// async global->LDS, 16 B per lane; LDS dst = wave-uniform base + lane*16
__device__ __forceinline__ void gload_lds16(const unsigned short* g,
                                            unsigned short* l) {
    __builtin_amdgcn_global_load_lds(
        (const __attribute__((address_space(1))) unsigned int*)g,
        (__attribute__((address_space(3))) unsigned int*)l, 16, 0, 0);
}

// ---------------------------------------------------------------------------
// fp32 -> bf16 conversion, 4 elems/thread
// ---------------------------------------------------------------------------
__global__ void cvt_f32_bf16(const float* __restrict__ in,
                             unsigned short* __restrict__ out, int n4) {
    int i = blockIdx.x * blockDim.x + threadIdx.x;
    if (i >= n4) return;
    float4 v = ((const float4*)in)[i];
    ushort4 o;
    o.x = f2b(v.x); o.y = f2b(v.y); o.z = f2b(v.z); o.w = f2b(v.w);
    ((ushort4*)out)[i] = o;
}

// ---------------------------------------------------------------------------
// m97-structure NT GEMM (unchanged from round 3/4).
// ---------------------------------------------------------------------------
template <typename CT>
__global__ void gemm_nt_lds(const unsigned short* __restrict__ A,
                            const unsigned short* __restrict__ B,
                            CT* __restrict__ C, int M, int N, int K) {
    __shared__ unsigned short Alds[128][32];
    __shared__ unsigned short Blds[128][32];

    const int tid  = threadIdx.x;
    const int lane = tid & 63;
    const int w    = tid >> 6;
    const int wm   = (w & 1) * 64;
    const int wn   = (w >> 1) * 64;

    const int m0 = blockIdx.x * 128;
    const int n0 = blockIdx.y * 128;

    const int row16 = lane & 15;
    const int part  = lane >> 4;
    const int rbase = part * 4;

    const int srow = lane >> 2;
    const int scol = (lane & 3) * 8;

    const unsigned short* Ag = A + (size_t)(m0 + w * 16 + srow) * K + scol;
    const unsigned short* Bg = B + (size_t)(n0 + w * 16 + srow) * K + scol;
    unsigned short* Al = &Alds[w * 16][0];
    unsigned short* Bl = &Blds[w * 16][0];
    const size_t rstep = (size_t)64 * K;

    floatx4 acc[4][4] = {};

    for (int k0 = 0; k0 < K; k0 += 32) {
        __syncthreads();
        gload_lds16(Ag + k0,         Al);
        gload_lds16(Ag + rstep + k0, Al + 64 * 32);
        gload_lds16(Bg + k0,         Bl);
        gload_lds16(Bg + rstep + k0, Bl + 64 * 32);
        __syncthreads();

        bf16x8 af[4], bfr[4];
#pragma unroll
        for (int i = 0; i < 4; ++i)
            af[i] = *(const bf16x8*)&Alds[wm + i * 16 + row16][part * 8];
#pragma unroll
        for (int j = 0; j < 4; ++j)
            bfr[j] = *(const bf16x8*)&Blds[wn + j * 16 + row16][part * 8];
#pragma unroll
        for (int i = 0; i < 4; ++i)
#pragma unroll
            for (int j = 0; j < 4; ++j)
                acc[i][j] = __builtin_amdgcn_mfma_f32_16x16x32_bf16(
                    af[i], bfr[j], acc[i][j], 0, 0, 0);
    }

#pragma unroll
    for (int i = 0; i < 4; ++i) {
#pragma unroll
        for (int j = 0; j < 4; ++j) {
            const int row = m0 + wm + i * 16 + rbase;
            const int col = n0 + wn + j * 16 + row16;
#pragma unroll
            for (int r = 0; r < 4; ++r) {
                size_t idx = (size_t)(row + r) * N + col;
                if constexpr (sizeof(CT) == 2) C[idx] = f2b(acc[i][j][r]);
                else                           C[idx] = acc[i][j][r];
            }
        }
    }
}

// ---------------------------------------------------------------------------
// repack_kv (unchanged from round 4): lane-linear MFMA-ready K / V^T tiles.
// ---------------------------------------------------------------------------
__global__ void repack_kv(const unsigned short* __restrict__ qkv,
                          unsigned short* __restrict__ Kp,
                          unsigned short* __restrict__ Vt) {
    __shared__ unsigned short Vs[64][72];
    const int st = blockIdx.x, h = blockIdx.y, b = blockIdx.z;
    const int tid = threadIdx.x;
    const size_t base = ((size_t)((b * HH + h) * (SS / 64) + st)) * 4096;

#pragma unroll
    for (int p = 0; p < 2; ++p) {
        const int row = p * 32 + (tid >> 3);
        const int chunk = tid & 7;
        size_t src = (size_t)(b * SS + st * 64 + row) * (3 * DD) +
                     DD + h * DKK + chunk * 8;
        uint4 kv = *(const uint4*)(qkv + src);
        *(uint4*)(Kp + base + (chunk >> 2) * 2048 + row * 32 + (chunk & 3) * 8) = kv;
        uint4 vv = *(const uint4*)(qkv + src + DD);
        *(uint4*)&Vs[row][chunk * 8] = vv;
    }
    __syncthreads();
#pragma unroll
    for (int p = 0; p < 2; ++p) {
        const int dk = p * 32 + (tid >> 3);
        const int s8 = tid & 7;
        union { unsigned short u[8]; uint4 v; } pk;
#pragma unroll
        for (int j = 0; j < 8; ++j) pk.u[j] = Vs[s8 * 8 + j][dk];
        *(uint4*)(Vt + base + (s8 >> 2) * 2048 + dk * 32 + (s8 & 3) * 8) = pk.v;
    }
}

// ---------------------------------------------------------------------------
// MFMA flash attention v3 (causal). BR=128, BC=64. Swapped QK^T operands:
// S^T = mfma(A=K, B=Q) -> C layout puts a full q-row in one lane
// (q=lane&15, k=kt*16+rbase+r). Softmax fully in-register; P A-fragment
// rebuilt via packed-pair shuffles. No score LDS (16.4 KB total).
// ---------------------------------------------------------------------------
#define ABR 128
#define ABC 64

__global__ __launch_bounds__(256) void attn_mfma3(
    const unsigned short* __restrict__ qkv,
    const unsigned short* __restrict__ Kp,
    const unsigned short* __restrict__ Vt,
    unsigned short* __restrict__ heads) {
    __shared__ unsigned short Kl[4096];   // [2 dk-chunk][64 s][32 dk]
    __shared__ unsigned short Vtl[4096];  // [2 s-chunk][64 dk][32 s]

    const int tid  = threadIdx.x;
    const int lane = tid & 63;
    const int w    = tid >> 6;
    const int h = blockIdx.y, b = blockIdx.z;
    const int bx = gridDim.x - 1 - blockIdx.x;  // hardest blocks first
    const int q0b = bx * ABR;
    const int q0w = q0b + w * 32;

    const int row16 = lane & 15;
    const int part  = lane >> 4;
    const int rbase = part * 4;

    const float c1 = 0.180336884f;  // 0.125 * log2(e)

    bf16x8 qf[2][2];
#pragma unroll
    for (int qt = 0; qt < 2; ++qt)
#pragma unroll
        for (int u = 0; u < 2; ++u)
            qf[qt][u] = *(const bf16x8*)(qkv +
                (size_t)(b * SS + q0w + qt * 16 + row16) * (3 * DD) +
                h * DKK + u * 32 + part * 8);

    floatx4 O[2][4] = {};
    float mrow[2] = {-1e30f, -1e30f}, lrow[2] = {0.f, 0.f};

    const int ntiles = (q0b + ABR) / ABC;
    const size_t tb = ((size_t)(b * HH + h) * (SS / 64)) * 4096;

    for (int t = 0; t < ntiles; ++t) {
        const int k0 = t * ABC;
        __syncthreads();
        {
            const unsigned short* ks = Kp + tb + (size_t)t * 4096 + w * 1024 + lane * 8;
            const unsigned short* vs = Vt + tb + (size_t)t * 4096 + w * 1024 + lane * 8;
            gload_lds16(ks,       Kl + w * 1024);
            gload_lds16(ks + 512, Kl + w * 1024 + 512);
            gload_lds16(vs,       Vtl + w * 1024);
            gload_lds16(vs + 512, Vtl + w * 1024 + 512);
        }
        __syncthreads();

        if (k0 > q0w + 31) continue;

        // K fragments (A-operand): m = k-row = kt*16+row16, dk chunk u
        bf16x8 kf[2][4];
#pragma unroll
        for (int u = 0; u < 2; ++u)
#pragma unroll
            for (int kt = 0; kt < 4; ++kt)
                kf[u][kt] = *(const bf16x8*)&Kl[u * 2048 +
                    (kt * 16 + row16) * 32 + part * 8];

#pragma unroll
        for (int qt = 0; qt < 2; ++qt) {
            // ---- S^T = K . Q^T : lane holds q=row16, k=kt*16+rbase+r ----
            floatx4 sc[4] = {};
#pragma unroll
            for (int u = 0; u < 2; ++u)
#pragma unroll
                for (int kt = 0; kt < 4; ++kt)
                    sc[kt] = __builtin_amdgcn_mfma_f32_16x16x32_bf16(
                        kf[u][kt], qf[qt][u], sc[kt], 0, 0, 0);

            // mask + scale (log2 domain), row max
            const int qa = q0w + qt * 16 + row16;
            const bool full = (k0 + 63 <= q0w + qt * 16);
            float mx = -1e30f;
#pragma unroll
            for (int kt = 0; kt < 4; ++kt)
#pragma unroll
                for (int r = 0; r < 4; ++r) {
                    float s = sc[kt][r] * c1;
                    if (!full) {
                        int ka = k0 + kt * 16 + rbase + r;
                        s = (ka <= qa) ? s : -1e30f;
                    }
                    sc[kt][r] = s;
                    mx = fmaxf(mx, s);
                }
            mx = fmaxf(mx, __shfl_xor(mx, 16));
            mx = fmaxf(mx, __shfl_xor(mx, 32));
            float mnew = fmaxf(mrow[qt], mx);
            float alpha = EXP2(mrow[qt] - mnew);

            // exp + pack bf16 pairs: pk[kt][t2] = (e[2t2], e[2t2+1])
            float ps = 0.f;
            unsigned int pk[4][2];
#pragma unroll
            for (int kt = 0; kt < 4; ++kt) {
                float e0 = EXP2(sc[kt][0] - mnew);
                float e1 = EXP2(sc[kt][1] - mnew);
                float e2 = EXP2(sc[kt][2] - mnew);
                float e3 = EXP2(sc[kt][3] - mnew);
                ps += (e0 + e1) + (e2 + e3);
                pk[kt][0] = (unsigned int)f2b(e0) | ((unsigned int)f2b(e1) << 16);
                pk[kt][1] = (unsigned int)f2b(e2) | ((unsigned int)f2b(e3) << 16);
            }
            ps += __shfl_xor(ps, 16);
            ps += __shfl_xor(ps, 32);
            lrow[qt] = lrow[qt] * alpha + ps;
            mrow[qt] = mnew;

            // rescale O (per C-row alpha)
            float a0 = __shfl(alpha, rbase + 0);
            float a1 = __shfl(alpha, rbase + 1);
            float a2 = __shfl(alpha, rbase + 2);
            float a3 = __shfl(alpha, rbase + 3);
#pragma unroll
            for (int dt = 0; dt < 4; ++dt) {
                O[qt][dt][0] *= a0; O[qt][dt][1] *= a1;
                O[qt][dt][2] *= a2; O[qt][dt][3] *= a3;
            }

            // ---- build P A-frags (m=q=row16, k=u*32+part*8+j) + PV ----
#pragma unroll
            for (int u = 0; u < 2; ++u) {
                union { unsigned int u32[4]; bf16x8 v; } P;
#pragma unroll
                for (int g = 0; g < 2; ++g)
#pragma unroll
                    for (int t2 = 0; t2 < 2; ++t2) {
                        int sl = ((part & 1) * 2 + g) * 16 + row16;
                        unsigned int v0 = (unsigned int)__shfl((int)pk[2 * u][t2], sl);
                        unsigned int v1 = (unsigned int)__shfl((int)pk[2 * u + 1][t2], sl);
                        P.u32[g * 2 + t2] = (part < 2) ? v0 : v1;
                    }
#pragma unroll
                for (int dt = 0; dt < 4; ++dt) {
                    bf16x8 vf = *(const bf16x8*)&Vtl[u * 2048 +
                        (dt * 16 + row16) * 32 + part * 8];
                    O[qt][dt] = __builtin_amdgcn_mfma_f32_16x16x32_bf16(
                        P.v, vf, O[qt][dt], 0, 0, 0);
                }
            }
        }
    }

    // epilogue: normalize + store merged-head bf16
#pragma unroll
    for (int qt = 0; qt < 2; ++qt) {
        float li0 = 1.f / __shfl(lrow[qt], rbase + 0);
        float li1 = 1.f / __shfl(lrow[qt], rbase + 1);
        float li2 = 1.f / __shfl(lrow[qt], rbase + 2);
        float li3 = 1.f / __shfl(lrow[qt], rbase + 3);
#pragma unroll
        for (int dt = 0; dt < 4; ++dt) {
            int dk = dt * 16 + row16;
            size_t base = (size_t)(b * SS + q0w + qt * 16 + rbase) * DD +
                          h * DKK + dk;
            heads[base]          = f2b(O[qt][dt][0] * li0);
            heads[base + DD]     = f2b(O[qt][dt][1] * li1);
            heads[base + 2 * DD] = f2b(O[qt][dt][2] * li2);
            heads[base + 3 * DD] = f2b(O[qt][dt][3] * li3);
        }
    }
}

// ---------------------------------------------------------------------------
extern "C" void kernel_launch(void* const* d_in, const int* in_sizes, int n_in,
                              void* d_out, int out_size, void* d_ws,
                              size_t ws_size, hipStream_t stream) {
    const float* x    = (const float*)d_in[0];
    const float* Wqkv = (const float*)d_in[1];
    const float* Wo   = (const float*)d_in[2];
    float* out = (float*)d_out;

    const size_t NX  = (size_t)BB * SS * DD;
    const size_t NWQ = (size_t)3 * DD * DD;
    const size_t NWO = (size_t)DD * DD;
    const size_t NKV = (size_t)BB * HH * SS * DKK;

    unsigned short* xb     = (unsigned short*)d_ws;
    unsigned short* wqkvb  = xb + NX;
    unsigned short* wob    = wqkvb + NWQ;
    unsigned short* qkvb   = wob + NWO;
    unsigned short* headsb = qkvb + (size_t)BB * SS * 3 * DD;
    unsigned short* Kp     = headsb + NX;
    unsigned short* Vtp    = Kp + NKV;

    cvt_f32_bf16<<<(int)(NX / 4 / 256), 256, 0, stream>>>(x, xb, (int)(NX / 4));
    cvt_f32_bf16<<<(int)(NWQ / 4 / 256), 256, 0, stream>>>(Wqkv, wqkvb, (int)(NWQ / 4));
    cvt_f32_bf16<<<(int)(NWO / 4 / 256), 256, 0, stream>>>(Wo, wob, (int)(NWO / 4));

    // QKV projection
    gemm_nt_lds<unsigned short><<<dim3(BB * SS / 128, 3 * DD / 128), 256, 0,
                                  stream>>>(xb, wqkvb, qkvb, BB * SS, 3 * DD, DD);

    // repack K/V into MFMA-ready lane-linear tiles
    repack_kv<<<dim3(SS / 64, HH, BB), 256, 0, stream>>>(qkvb, Kp, Vtp);

    // causal MFMA attention
    attn_mfma3<<<dim3(SS / ABR, HH, BB), 256, 0, stream>>>(qkvb, Kp, Vtp, headsb);

    // output projection
    gemm_nt_lds<float><<<dim3(BB * SS / 128, DD / 128), 256, 0, stream>>>(
        headsb, wob, out, BB * SS, DD, DD);
}

// Round 7
// 319.690 us; speedup vs baseline: 1.1815x; 1.1815x over previous
//
#include <hip/hip_runtime.h>
#include <hip/hip_bf16.h>

// Problem constants (B=4, S=2048, D=1024, H=16, DK=64)
#define BB 4
#define SS 2048
#define DD 1024
#define HH 16
#define DKK 64

typedef __bf16 bf16x8 __attribute__((ext_vector_type(8)));
typedef float floatx4 __attribute__((ext_vector_type(4)));

#if __has_builtin(__builtin_amdgcn_exp2f)
#define EXP2(x) __builtin_amdgcn_exp2f(x)
#else
#define EXP2(x) exp2f(x)
#endif

__device__ __forceinline__ float b2f(unsigned short u) {
    union { unsigned int i; float f; } c;
    c.i = ((unsigned int)u) << 16;
    return c.f;
}
__device__ __forceinline__ unsigned short f2b(float f) {
    unsigned int i = __float_as_uint(f);
    unsigned int r = (i + 0x7FFFu + ((i >> 16) & 1u)) >> 16;  // RNE
    return (unsigned short)r;
}

// async global->LDS, 16 B per lane; LDS dst = wave-uniform base + lane*16
__device__ __forceinline__ void gload_lds16(const unsigned short* g,
                                            unsigned short* l) {
    __builtin_amdgcn_global_load_lds(
        (const __attribute__((address_space(1))) unsigned int*)g,
        (__attribute__((address_space(3))) unsigned int*)l, 16, 0, 0);
}

// ---------------------------------------------------------------------------
// fp32 -> bf16 conversion, 4 elems/thread
// ---------------------------------------------------------------------------
__global__ void cvt_f32_bf16(const float* __restrict__ in,
                             unsigned short* __restrict__ out, int n4) {
    int i = blockIdx.x * blockDim.x + threadIdx.x;
    if (i >= n4) return;
    float4 v = ((const float4*)in)[i];
    ushort4 o;
    o.x = f2b(v.x); o.y = f2b(v.y); o.z = f2b(v.z); o.w = f2b(v.w);
    ((ushort4*)out)[i] = o;
}

// ---------------------------------------------------------------------------
// m97-structure NT GEMM (unchanged; ~736 TF measured round 3).
// ---------------------------------------------------------------------------
template <typename CT>
__global__ void gemm_nt_lds(const unsigned short* __restrict__ A,
                            const unsigned short* __restrict__ B,
                            CT* __restrict__ C, int M, int N, int K) {
    __shared__ unsigned short Alds[128][32];
    __shared__ unsigned short Blds[128][32];

    const int tid  = threadIdx.x;
    const int lane = tid & 63;
    const int w    = tid >> 6;
    const int wm   = (w & 1) * 64;
    const int wn   = (w >> 1) * 64;

    const int m0 = blockIdx.x * 128;
    const int n0 = blockIdx.y * 128;

    const int row16 = lane & 15;
    const int part  = lane >> 4;
    const int rbase = part * 4;

    const int srow = lane >> 2;
    const int scol = (lane & 3) * 8;

    const unsigned short* Ag = A + (size_t)(m0 + w * 16 + srow) * K + scol;
    const unsigned short* Bg = B + (size_t)(n0 + w * 16 + srow) * K + scol;
    unsigned short* Al = &Alds[w * 16][0];
    unsigned short* Bl = &Blds[w * 16][0];
    const size_t rstep = (size_t)64 * K;

    floatx4 acc[4][4] = {};

    for (int k0 = 0; k0 < K; k0 += 32) {
        __syncthreads();
        gload_lds16(Ag + k0,         Al);
        gload_lds16(Ag + rstep + k0, Al + 64 * 32);
        gload_lds16(Bg + k0,         Bl);
        gload_lds16(Bg + rstep + k0, Bl + 64 * 32);
        __syncthreads();

        bf16x8 af[4], bfr[4];
#pragma unroll
        for (int i = 0; i < 4; ++i)
            af[i] = *(const bf16x8*)&Alds[wm + i * 16 + row16][part * 8];
#pragma unroll
        for (int j = 0; j < 4; ++j)
            bfr[j] = *(const bf16x8*)&Blds[wn + j * 16 + row16][part * 8];
#pragma unroll
        for (int i = 0; i < 4; ++i)
#pragma unroll
            for (int j = 0; j < 4; ++j)
                acc[i][j] = __builtin_amdgcn_mfma_f32_16x16x32_bf16(
                    af[i], bfr[j], acc[i][j], 0, 0, 0);
    }

#pragma unroll
    for (int i = 0; i < 4; ++i) {
#pragma unroll
        for (int j = 0; j < 4; ++j) {
            const int row = m0 + wm + i * 16 + rbase;
            const int col = n0 + wn + j * 16 + row16;
#pragma unroll
            for (int r = 0; r < 4; ++r) {
                size_t idx = (size_t)(row + r) * N + col;
                if constexpr (sizeof(CT) == 2) C[idx] = f2b(acc[i][j][r]);
                else                           C[idx] = acc[i][j][r];
            }
        }
    }
}

// ---------------------------------------------------------------------------
// repack_kv (unchanged): lane/fragment-linear K / V^T tiles per (b,h,stile64).
//  Kp tile [u=dk32-chunk][64 s][32 dk], Vt tile [u=s32-chunk][64 dk][32 s].
// ---------------------------------------------------------------------------
__global__ void repack_kv(const unsigned short* __restrict__ qkv,
                          unsigned short* __restrict__ Kp,
                          unsigned short* __restrict__ Vt) {
    __shared__ unsigned short Vs[64][72];
    const int st = blockIdx.x, h = blockIdx.y, b = blockIdx.z;
    const int tid = threadIdx.x;
    const size_t base = ((size_t)((b * HH + h) * (SS / 64) + st)) * 4096;

#pragma unroll
    for (int p = 0; p < 2; ++p) {
        const int row = p * 32 + (tid >> 3);
        const int chunk = tid & 7;
        size_t src = (size_t)(b * SS + st * 64 + row) * (3 * DD) +
                     DD + h * DKK + chunk * 8;
        uint4 kv = *(const uint4*)(qkv + src);
        *(uint4*)(Kp + base + (chunk >> 2) * 2048 + row * 32 + (chunk & 3) * 8) = kv;
        uint4 vv = *(const uint4*)(qkv + src + DD);
        *(uint4*)&Vs[row][chunk * 8] = vv;
    }
    __syncthreads();
#pragma unroll
    for (int p = 0; p < 2; ++p) {
        const int dk = p * 32 + (tid >> 3);
        const int s8 = tid & 7;
        union { unsigned short u[8]; uint4 v; } pk;
#pragma unroll
        for (int j = 0; j < 8; ++j) pk.u[j] = Vs[s8 * 8 + j][dk];
        *(uint4*)(Vt + base + (s8 >> 2) * 2048 + dk * 32 + (s8 & 3) * 8) = pk.v;
    }
}

// ---------------------------------------------------------------------------
// MFMA flash attention v5 (causal): NO LDS, NO barriers. Each wave owns 32
// q rows; K/V fragments global->VGPR from fragment-linear Kp/Vt (L2 reuse).
//  S^T = mfma(A=K, B=Q): lane holds q=lane&15 fixed, s = kt*16+rbase+r.
//  O^T = mfma(A=V^T, B=P^T): same per-lane q; m/l/alpha all per-lane.
//  P^T B-frag reg t (s = u*32+part*8+2t,+1): source lane row16+((part&1)*2
//   +(t>>1))*16, register pk[2u+(part>>1)][t&1]. The kt-select depends on
//   the DESTINATION's part -> must happen AFTER the shuffle (round-6 bug:
//   pre-shuffle select used the source lane's part -> scrambled P).
// ---------------------------------------------------------------------------
__global__ __launch_bounds__(256) void attn_mfma5(
    const unsigned short* __restrict__ qkv,
    const unsigned short* __restrict__ Kp,
    const unsigned short* __restrict__ Vt,
    unsigned short* __restrict__ heads) {
    const int tid  = threadIdx.x;
    const int lane = tid & 63;
    const int w    = tid >> 6;

    // XCD-aware mapping: pair (b*16+h) pinned to xcd = blockIdx.x & 7
    const int u0   = blockIdx.x;              // 0..1023
    const int xcd  = u0 & 7;
    const int slot = u0 >> 3;                 // 0..127
    const int pair = xcd * 8 + (slot >> 4);   // 0..63 = b*16+h
    const int qx   = 15 - (slot & 15);        // heavy-first within pair
    const int b = pair >> 4, h = pair & 15;
    const int q0w = qx * 128 + w * 32;

    const int row16 = lane & 15;   // q (C col) / fragment free index
    const int part  = lane >> 4;
    const int rbase = part * 4;
    const float c1 = 0.180336884f;  // 0.125 * log2(e)

    // Q fragments, pre-scaled by c1 (folded into bf16 once)
    bf16x8 qf[2][2];
#pragma unroll
    for (int qt = 0; qt < 2; ++qt)
#pragma unroll
        for (int u = 0; u < 2; ++u) {
            const unsigned short* qp = qkv +
                (size_t)(b * SS + q0w + qt * 16 + row16) * (3 * DD) +
                h * DKK + u * 32 + part * 8;
            union { uint4 r; unsigned short us[8]; } raw;
            raw.r = *(const uint4*)qp;
            union { unsigned short us[8]; bf16x8 v; } sq;
#pragma unroll
            for (int j = 0; j < 8; ++j) sq.us[j] = f2b(b2f(raw.us[j]) * c1);
            qf[qt][u] = sq.v;
        }

    floatx4 O[2][4] = {};   // O^T: lane(q=row16) x [dt] -> dk=dt*16+rbase+r
    float mrow[2] = {-1e30f, -1e30f}, lrow[2] = {0.f, 0.f};

    const size_t tb = (size_t)pair * (SS / 64) * 4096;
    const int ntiles = (q0w + 31) / 64 + 1;

    for (int t = 0; t < ntiles; ++t) {
        const int k0 = t * 64;
        const unsigned short* kbase = Kp + tb + (size_t)t * 4096;
        const unsigned short* vbase = Vt + tb + (size_t)t * 4096;
        bf16x8 kf[2][4], vf[2][4];
#pragma unroll
        for (int u = 0; u < 2; ++u)
#pragma unroll
            for (int i = 0; i < 4; ++i) {
                kf[u][i] = *(const bf16x8*)(kbase + u * 2048 +
                                            (i * 16 + row16) * 32 + part * 8);
                vf[u][i] = *(const bf16x8*)(vbase + u * 2048 +
                                            (i * 16 + row16) * 32 + part * 8);
            }

#pragma unroll
        for (int qt = 0; qt < 2; ++qt) {
            // ---- S^T: lane holds q=row16, s = kt*16 + rbase + r ----
            floatx4 sc[4] = {};
#pragma unroll
            for (int u = 0; u < 2; ++u)
#pragma unroll
                for (int kt = 0; kt < 4; ++kt)
                    sc[kt] = __builtin_amdgcn_mfma_f32_16x16x32_bf16(
                        kf[u][kt], qf[qt][u], sc[kt], 0, 0, 0);

            const int qa = q0w + qt * 16 + row16;
            const bool full = (k0 + 63 <= q0w + qt * 16);
            float mx = -1e30f;
#pragma unroll
            for (int kt = 0; kt < 4; ++kt)
#pragma unroll
                for (int r = 0; r < 4; ++r) {
                    float s = sc[kt][r];  // already log2-scaled via Q
                    if (!full) {
                        int ka = k0 + kt * 16 + rbase + r;
                        s = (ka <= qa) ? s : -1e30f;
                    }
                    sc[kt][r] = s;
                    mx = fmaxf(mx, s);
                }
            mx = fmaxf(mx, __shfl_xor(mx, 16));
            mx = fmaxf(mx, __shfl_xor(mx, 32));
            float mnew = fmaxf(mrow[qt], mx);
            float alpha = EXP2(mrow[qt] - mnew);

            float ps = 0.f;
            unsigned int pk[4][2];
#pragma unroll
            for (int kt = 0; kt < 4; ++kt) {
                float e0 = EXP2(sc[kt][0] - mnew);
                float e1 = EXP2(sc[kt][1] - mnew);
                float e2 = EXP2(sc[kt][2] - mnew);
                float e3 = EXP2(sc[kt][3] - mnew);
                ps += (e0 + e1) + (e2 + e3);
                pk[kt][0] = (unsigned int)f2b(e0) | ((unsigned int)f2b(e1) << 16);
                pk[kt][1] = (unsigned int)f2b(e2) | ((unsigned int)f2b(e3) << 16);
            }
            ps += __shfl_xor(ps, 16);
            ps += __shfl_xor(ps, 32);
            lrow[qt] = lrow[qt] * alpha + ps;
            mrow[qt] = mnew;

            // O^T rescale: alpha per-lane (q fixed) -> uniform multiply
#pragma unroll
            for (int dt = 0; dt < 4; ++dt) O[qt][dt] *= alpha;

            // ---- P^T B-frags (select AFTER shuffle) + PV^T ----
            const int l0 = row16 + ((part & 1) * 2 + 0) * 16;
            const int l1 = row16 + ((part & 1) * 2 + 1) * 16;
            const bool hi = (part >> 1);
#pragma unroll
            for (int u = 0; u < 2; ++u) {
                unsigned int lo00 = (unsigned int)__shfl((int)pk[2 * u][0], l0);
                unsigned int lo01 = (unsigned int)__shfl((int)pk[2 * u][1], l0);
                unsigned int lo10 = (unsigned int)__shfl((int)pk[2 * u][0], l1);
                unsigned int lo11 = (unsigned int)__shfl((int)pk[2 * u][1], l1);
                unsigned int hi00 = (unsigned int)__shfl((int)pk[2 * u + 1][0], l0);
                unsigned int hi01 = (unsigned int)__shfl((int)pk[2 * u + 1][1], l0);
                unsigned int hi10 = (unsigned int)__shfl((int)pk[2 * u + 1][0], l1);
                unsigned int hi11 = (unsigned int)__shfl((int)pk[2 * u + 1][1], l1);
                union { unsigned int u32[4]; bf16x8 v; } P;
                P.u32[0] = hi ? hi00 : lo00;
                P.u32[1] = hi ? hi01 : lo01;
                P.u32[2] = hi ? hi10 : lo10;
                P.u32[3] = hi ? hi11 : lo11;
#pragma unroll
                for (int dt = 0; dt < 4; ++dt)
                    O[qt][dt] = __builtin_amdgcn_mfma_f32_16x16x32_bf16(
                        vf[u][dt], P.v, O[qt][dt], 0, 0, 0);
            }
        }
    }

    // epilogue: normalize (in-lane l) + vectorized store
#pragma unroll
    for (int qt = 0; qt < 2; ++qt) {
        float inv = 1.f / lrow[qt];
#pragma unroll
        for (int dt = 0; dt < 4; ++dt) {
            ushort4 o4;
            o4.x = f2b(O[qt][dt][0] * inv);
            o4.y = f2b(O[qt][dt][1] * inv);
            o4.z = f2b(O[qt][dt][2] * inv);
            o4.w = f2b(O[qt][dt][3] * inv);
            size_t base = (size_t)(b * SS + q0w + qt * 16 + row16) * DD +
                          h * DKK + dt * 16 + rbase;
            *(ushort4*)&heads[base] = o4;
        }
    }
}

// ---------------------------------------------------------------------------
extern "C" void kernel_launch(void* const* d_in, const int* in_sizes, int n_in,
                              void* d_out, int out_size, void* d_ws,
                              size_t ws_size, hipStream_t stream) {
    const float* x    = (const float*)d_in[0];
    const float* Wqkv = (const float*)d_in[1];
    const float* Wo   = (const float*)d_in[2];
    float* out = (float*)d_out;

    const size_t NX  = (size_t)BB * SS * DD;
    const size_t NWQ = (size_t)3 * DD * DD;
    const size_t NWO = (size_t)DD * DD;
    const size_t NKV = (size_t)BB * HH * SS * DKK;

    unsigned short* xb     = (unsigned short*)d_ws;
    unsigned short* wqkvb  = xb + NX;
    unsigned short* wob    = wqkvb + NWQ;
    unsigned short* qkvb   = wob + NWO;
    unsigned short* headsb = qkvb + (size_t)BB * SS * 3 * DD;
    unsigned short* Kp     = headsb + NX;
    unsigned short* Vtp    = Kp + NKV;

    cvt_f32_bf16<<<(int)(NX / 4 / 256), 256, 0, stream>>>(x, xb, (int)(NX / 4));
    cvt_f32_bf16<<<(int)(NWQ / 4 / 256), 256, 0, stream>>>(Wqkv, wqkvb, (int)(NWQ / 4));
    cvt_f32_bf16<<<(int)(NWO / 4 / 256), 256, 0, stream>>>(Wo, wob, (int)(NWO / 4));

    // QKV projection
    gemm_nt_lds<unsigned short><<<dim3(BB * SS / 128, 3 * DD / 128), 256, 0,
                                  stream>>>(xb, wqkvb, qkvb, BB * SS, 3 * DD, DD);

    // repack K/V into MFMA-ready fragment-linear tiles
    repack_kv<<<dim3(SS / 64, HH, BB), 256, 0, stream>>>(qkvb, Kp, Vtp);

    // causal MFMA attention (LDS-free, barrier-free)
    attn_mfma5<<<dim3(1024), 256, 0, stream>>>(qkvb, Kp, Vtp, headsb);

    // output projection
    gemm_nt_lds<float><<<dim3(BB * SS / 128, DD / 128), 256, 0, stream>>>(
        headsb, wob, out, BB * SS, DD, DD);
}

// Round 8
// 269.680 us; speedup vs baseline: 1.4006x; 1.1854x over previous
//
#include <hip/hip_runtime.h>
#include <hip/hip_bf16.h>

// Problem constants (B=4, S=2048, D=1024, H=16, DK=64)
#define BB 4
#define SS 2048
#define DD 1024
#define HH 16
#define DKK 64

typedef __bf16 bf16x8 __attribute__((ext_vector_type(8)));
typedef float floatx4 __attribute__((ext_vector_type(4)));

#if __has_builtin(__builtin_amdgcn_exp2f)
#define EXP2(x) __builtin_amdgcn_exp2f(x)
#else
#define EXP2(x) exp2f(x)
#endif

__device__ __forceinline__ float b2f(unsigned short u) {
    union { unsigned int i; float f; } c;
    c.i = ((unsigned int)u) << 16;
    return c.f;
}
__device__ __forceinline__ unsigned short f2b(float f) {
    unsigned int i = __float_as_uint(f);
    unsigned int r = (i + 0x7FFFu + ((i >> 16) & 1u)) >> 16;  // RNE
    return (unsigned short)r;
}
// cheap round-half-up bf16 pair pack: (lo, hi) -> u32
__device__ __forceinline__ unsigned int pkpair(float a, float b) {
    unsigned int ia = (__float_as_uint(a) + 0x8000u) >> 16;
    unsigned int ib = (__float_as_uint(b) + 0x8000u) & 0xffff0000u;
    return ia | ib;
}

// async global->LDS, 16 B per lane; LDS dst = wave-uniform base + lane*16
__device__ __forceinline__ void gload_lds16(const unsigned short* g,
                                            unsigned short* l) {
    __builtin_amdgcn_global_load_lds(
        (const __attribute__((address_space(1))) unsigned int*)g,
        (__attribute__((address_space(3))) unsigned int*)l, 16, 0, 0);
}

// ---------------------------------------------------------------------------
// fp32 -> bf16 conversion, 4 elems/thread
// ---------------------------------------------------------------------------
__global__ void cvt_f32_bf16(const float* __restrict__ in,
                             unsigned short* __restrict__ out, int n4) {
    int i = blockIdx.x * blockDim.x + threadIdx.x;
    if (i >= n4) return;
    float4 v = ((const float4*)in)[i];
    ushort4 o;
    o.x = f2b(v.x); o.y = f2b(v.y); o.z = f2b(v.z); o.w = f2b(v.w);
    ((ushort4*)out)[i] = o;
}

// ---------------------------------------------------------------------------
// m97-structure NT GEMM (unchanged).
// ---------------------------------------------------------------------------
template <typename CT>
__global__ void gemm_nt_lds(const unsigned short* __restrict__ A,
                            const unsigned short* __restrict__ B,
                            CT* __restrict__ C, int M, int N, int K) {
    __shared__ unsigned short Alds[128][32];
    __shared__ unsigned short Blds[128][32];

    const int tid  = threadIdx.x;
    const int lane = tid & 63;
    const int w    = tid >> 6;
    const int wm   = (w & 1) * 64;
    const int wn   = (w >> 1) * 64;

    const int m0 = blockIdx.x * 128;
    const int n0 = blockIdx.y * 128;

    const int row16 = lane & 15;
    const int part  = lane >> 4;
    const int rbase = part * 4;

    const int srow = lane >> 2;
    const int scol = (lane & 3) * 8;

    const unsigned short* Ag = A + (size_t)(m0 + w * 16 + srow) * K + scol;
    const unsigned short* Bg = B + (size_t)(n0 + w * 16 + srow) * K + scol;
    unsigned short* Al = &Alds[w * 16][0];
    unsigned short* Bl = &Blds[w * 16][0];
    const size_t rstep = (size_t)64 * K;

    floatx4 acc[4][4] = {};

    for (int k0 = 0; k0 < K; k0 += 32) {
        __syncthreads();
        gload_lds16(Ag + k0,         Al);
        gload_lds16(Ag + rstep + k0, Al + 64 * 32);
        gload_lds16(Bg + k0,         Bl);
        gload_lds16(Bg + rstep + k0, Bl + 64 * 32);
        __syncthreads();

        bf16x8 af[4], bfr[4];
#pragma unroll
        for (int i = 0; i < 4; ++i)
            af[i] = *(const bf16x8*)&Alds[wm + i * 16 + row16][part * 8];
#pragma unroll
        for (int j = 0; j < 4; ++j)
            bfr[j] = *(const bf16x8*)&Blds[wn + j * 16 + row16][part * 8];
#pragma unroll
        for (int i = 0; i < 4; ++i)
#pragma unroll
            for (int j = 0; j < 4; ++j)
                acc[i][j] = __builtin_amdgcn_mfma_f32_16x16x32_bf16(
                    af[i], bfr[j], acc[i][j], 0, 0, 0);
    }

#pragma unroll
    for (int i = 0; i < 4; ++i) {
#pragma unroll
        for (int j = 0; j < 4; ++j) {
            const int row = m0 + wm + i * 16 + rbase;
            const int col = n0 + wn + j * 16 + row16;
#pragma unroll
            for (int r = 0; r < 4; ++r) {
                size_t idx = (size_t)(row + r) * N + col;
                if constexpr (sizeof(CT) == 2) C[idx] = f2b(acc[i][j][r]);
                else                           C[idx] = acc[i][j][r];
            }
        }
    }
}

// ---------------------------------------------------------------------------
// repack_kv (unchanged): fragment-linear K / V^T tiles per (b,h,stile64).
// ---------------------------------------------------------------------------
__global__ void repack_kv(const unsigned short* __restrict__ qkv,
                          unsigned short* __restrict__ Kp,
                          unsigned short* __restrict__ Vt) {
    __shared__ unsigned short Vs[64][72];
    const int st = blockIdx.x, h = blockIdx.y, b = blockIdx.z;
    const int tid = threadIdx.x;
    const size_t base = ((size_t)((b * HH + h) * (SS / 64) + st)) * 4096;

#pragma unroll
    for (int p = 0; p < 2; ++p) {
        const int row = p * 32 + (tid >> 3);
        const int chunk = tid & 7;
        size_t src = (size_t)(b * SS + st * 64 + row) * (3 * DD) +
                     DD + h * DKK + chunk * 8;
        uint4 kv = *(const uint4*)(qkv + src);
        *(uint4*)(Kp + base + (chunk >> 2) * 2048 + row * 32 + (chunk & 3) * 8) = kv;
        uint4 vv = *(const uint4*)(qkv + src + DD);
        *(uint4*)&Vs[row][chunk * 8] = vv;
    }
    __syncthreads();
#pragma unroll
    for (int p = 0; p < 2; ++p) {
        const int dk = p * 32 + (tid >> 3);
        const int s8 = tid & 7;
        union { unsigned short u[8]; uint4 v; } pk;
#pragma unroll
        for (int j = 0; j < 8; ++j) pk.u[j] = Vs[s8 * 8 + j][dk];
        *(uint4*)(Vt + base + (s8 >> 2) * 2048 + dk * 32 + (s8 & 3) * 8) = pk.v;
    }
}

// ---------------------------------------------------------------------------
// MFMA flash attention v6 (causal): LDS/barrier-free (round-7 math) +
// COMPLEMENTARY STRIP PAIRING for perfect load balance. Wave slot j handles
// q-strips j and 63-j of one (b,h): ntiles sums to 33 for EVERY wave.
// K/V fragments loaded once per tile feed both strips (shared loads + ILP).
// Grid 512 blocks (2/CU), 2048 uniform waves.
// ---------------------------------------------------------------------------
struct StripState {
    bf16x8 qf[2][2];
    floatx4 O[2][4];
    float mrow[2], lrow[2];
    int q0w;
};

__device__ __forceinline__ void strip_init(
    StripState& S, const unsigned short* __restrict__ qkv,
    int b, int h, int q0w, int row16, int part) {
    const float c1 = 0.180336884f;  // 0.125 * log2(e)
    S.q0w = q0w;
#pragma unroll
    for (int qt = 0; qt < 2; ++qt) {
        S.mrow[qt] = -1e30f;
        S.lrow[qt] = 0.f;
#pragma unroll
        for (int dt = 0; dt < 4; ++dt) S.O[qt][dt] = floatx4{0, 0, 0, 0};
#pragma unroll
        for (int u = 0; u < 2; ++u) {
            const unsigned short* qp = qkv +
                (size_t)(b * SS + q0w + qt * 16 + row16) * (3 * DD) +
                h * DKK + u * 32 + part * 8;
            union { uint4 r; unsigned short us[8]; } raw;
            raw.r = *(const uint4*)qp;
            union { unsigned short us[8]; bf16x8 v; } sq;
#pragma unroll
            for (int j = 0; j < 8; ++j) sq.us[j] = f2b(b2f(raw.us[j]) * c1);
            S.qf[qt][u] = sq.v;
        }
    }
}

__device__ __forceinline__ void strip_tile(
    StripState& S, int k0, const bf16x8 kf[2][4], const bf16x8 vf[2][4],
    int row16, int part, int rbase) {
#pragma unroll
    for (int qt = 0; qt < 2; ++qt) {
        // ---- S^T: lane holds q=row16, s = kt*16 + rbase + r ----
        floatx4 sc[4] = {};
#pragma unroll
        for (int u = 0; u < 2; ++u)
#pragma unroll
            for (int kt = 0; kt < 4; ++kt)
                sc[kt] = __builtin_amdgcn_mfma_f32_16x16x32_bf16(
                    kf[u][kt], S.qf[qt][u], sc[kt], 0, 0, 0);

        const int qa = S.q0w + qt * 16 + row16;
        const bool full = (k0 + 63 <= S.q0w + qt * 16);
        float mx = -1e30f;
#pragma unroll
        for (int kt = 0; kt < 4; ++kt)
#pragma unroll
            for (int r = 0; r < 4; ++r) {
                float s = sc[kt][r];  // log2-scaled via Q
                if (!full) {
                    int ka = k0 + kt * 16 + rbase + r;
                    s = (ka <= qa) ? s : -1e30f;
                }
                sc[kt][r] = s;
                mx = fmaxf(mx, s);
            }
        mx = fmaxf(mx, __shfl_xor(mx, 16));
        mx = fmaxf(mx, __shfl_xor(mx, 32));
        float mnew = fmaxf(S.mrow[qt], mx);
        float alpha = EXP2(S.mrow[qt] - mnew);

        float ps = 0.f;
        unsigned int pk[4][2];
#pragma unroll
        for (int kt = 0; kt < 4; ++kt) {
            float e0 = EXP2(sc[kt][0] - mnew);
            float e1 = EXP2(sc[kt][1] - mnew);
            float e2 = EXP2(sc[kt][2] - mnew);
            float e3 = EXP2(sc[kt][3] - mnew);
            ps += (e0 + e1) + (e2 + e3);
            pk[kt][0] = pkpair(e0, e1);
            pk[kt][1] = pkpair(e2, e3);
        }
        ps += __shfl_xor(ps, 16);
        ps += __shfl_xor(ps, 32);
        S.lrow[qt] = S.lrow[qt] * alpha + ps;
        S.mrow[qt] = mnew;

#pragma unroll
        for (int dt = 0; dt < 4; ++dt) S.O[qt][dt] *= alpha;

        // ---- P^T B-frags (kt-select AFTER shuffle; dest-part algebra) ----
        const int l0 = row16 + ((part & 1) * 2 + 0) * 16;
        const int l1 = row16 + ((part & 1) * 2 + 1) * 16;
        const bool hi = (part >> 1);
#pragma unroll
        for (int u = 0; u < 2; ++u) {
            unsigned int lo00 = (unsigned int)__shfl((int)pk[2 * u][0], l0);
            unsigned int lo01 = (unsigned int)__shfl((int)pk[2 * u][1], l0);
            unsigned int lo10 = (unsigned int)__shfl((int)pk[2 * u][0], l1);
            unsigned int lo11 = (unsigned int)__shfl((int)pk[2 * u][1], l1);
            unsigned int hi00 = (unsigned int)__shfl((int)pk[2 * u + 1][0], l0);
            unsigned int hi01 = (unsigned int)__shfl((int)pk[2 * u + 1][1], l0);
            unsigned int hi10 = (unsigned int)__shfl((int)pk[2 * u + 1][0], l1);
            unsigned int hi11 = (unsigned int)__shfl((int)pk[2 * u + 1][1], l1);
            union { unsigned int u32[4]; bf16x8 v; } P;
            P.u32[0] = hi ? hi00 : lo00;
            P.u32[1] = hi ? hi01 : lo01;
            P.u32[2] = hi ? hi10 : lo10;
            P.u32[3] = hi ? hi11 : lo11;
#pragma unroll
            for (int dt = 0; dt < 4; ++dt)
                S.O[qt][dt] = __builtin_amdgcn_mfma_f32_16x16x32_bf16(
                    vf[u][dt], P.v, S.O[qt][dt], 0, 0, 0);
        }
    }
}

__device__ __forceinline__ void strip_store(
    StripState& S, unsigned short* __restrict__ heads,
    int b, int h, int row16, int rbase) {
#pragma unroll
    for (int qt = 0; qt < 2; ++qt) {
        float inv = 1.f / S.lrow[qt];
#pragma unroll
        for (int dt = 0; dt < 4; ++dt) {
            ushort4 o4;
            o4.x = f2b(S.O[qt][dt][0] * inv);
            o4.y = f2b(S.O[qt][dt][1] * inv);
            o4.z = f2b(S.O[qt][dt][2] * inv);
            o4.w = f2b(S.O[qt][dt][3] * inv);
            size_t base = (size_t)(b * SS + S.q0w + qt * 16 + row16) * DD +
                          h * DKK + dt * 16 + rbase;
            *(ushort4*)&heads[base] = o4;
        }
    }
}

__global__ __launch_bounds__(256, 2) void attn_mfma6(
    const unsigned short* __restrict__ qkv,
    const unsigned short* __restrict__ Kp,
    const unsigned short* __restrict__ Vt,
    unsigned short* __restrict__ heads) {
    const int tid  = threadIdx.x;
    const int lane = tid & 63;
    const int w    = tid >> 6;

    // XCD mapping: 8 blocks of one (b,h) pinned to xcd = bx & 7
    const int bx   = blockIdx.x;              // 0..511
    const int xcd  = bx & 7;
    const int slot = bx >> 3;                 // 0..63
    const int pair = xcd * 8 + (slot >> 3);   // 0..63 = b*16+h
    const int blk  = slot & 7;                // 0..7
    const int b = pair >> 4, h = pair & 15;

    const int jA = blk * 4 + w;               // 0..31 (light strip)
    const int jB = 63 - jA;                   // 32..63 (heavy strip)
    const int ntA = jA / 2 + 1;               // tiles for strip A
    const int ntB = jB / 2 + 1;               // tiles for strip B (>= 17)

    const int row16 = lane & 15;
    const int part  = lane >> 4;
    const int rbase = part * 4;

    StripState SA, SB;
    strip_init(SA, qkv, b, h, jA * 32, row16, part);
    strip_init(SB, qkv, b, h, jB * 32, row16, part);

    const size_t tb = (size_t)pair * (SS / 64) * 4096;

    for (int t = 0; t < ntB; ++t) {
        const int k0 = t * 64;
        const unsigned short* kbase = Kp + tb + (size_t)t * 4096;
        const unsigned short* vbase = Vt + tb + (size_t)t * 4096;
        bf16x8 kf[2][4], vf[2][4];
#pragma unroll
        for (int u = 0; u < 2; ++u)
#pragma unroll
            for (int i = 0; i < 4; ++i) {
                kf[u][i] = *(const bf16x8*)(kbase + u * 2048 +
                                            (i * 16 + row16) * 32 + part * 8);
                vf[u][i] = *(const bf16x8*)(vbase + u * 2048 +
                                            (i * 16 + row16) * 32 + part * 8);
            }
        strip_tile(SB, k0, kf, vf, row16, part, rbase);
        if (t < ntA) strip_tile(SA, k0, kf, vf, row16, part, rbase);
    }

    strip_store(SA, heads, b, h, row16, rbase);
    strip_store(SB, heads, b, h, row16, rbase);
}

// ---------------------------------------------------------------------------
extern "C" void kernel_launch(void* const* d_in, const int* in_sizes, int n_in,
                              void* d_out, int out_size, void* d_ws,
                              size_t ws_size, hipStream_t stream) {
    const float* x    = (const float*)d_in[0];
    const float* Wqkv = (const float*)d_in[1];
    const float* Wo   = (const float*)d_in[2];
    float* out = (float*)d_out;

    const size_t NX  = (size_t)BB * SS * DD;
    const size_t NWQ = (size_t)3 * DD * DD;
    const size_t NWO = (size_t)DD * DD;
    const size_t NKV = (size_t)BB * HH * SS * DKK;

    unsigned short* xb     = (unsigned short*)d_ws;
    unsigned short* wqkvb  = xb + NX;
    unsigned short* wob    = wqkvb + NWQ;
    unsigned short* qkvb   = wob + NWO;
    unsigned short* headsb = qkvb + (size_t)BB * SS * 3 * DD;
    unsigned short* Kp     = headsb + NX;
    unsigned short* Vtp    = Kp + NKV;

    cvt_f32_bf16<<<(int)(NX / 4 / 256), 256, 0, stream>>>(x, xb, (int)(NX / 4));
    cvt_f32_bf16<<<(int)(NWQ / 4 / 256), 256, 0, stream>>>(Wqkv, wqkvb, (int)(NWQ / 4));
    cvt_f32_bf16<<<(int)(NWO / 4 / 256), 256, 0, stream>>>(Wo, wob, (int)(NWO / 4));

    // QKV projection
    gemm_nt_lds<unsigned short><<<dim3(BB * SS / 128, 3 * DD / 128), 256, 0,
                                  stream>>>(xb, wqkvb, qkvb, BB * SS, 3 * DD, DD);

    // repack K/V into MFMA-ready fragment-linear tiles
    repack_kv<<<dim3(SS / 64, HH, BB), 256, 0, stream>>>(qkvb, Kp, Vtp);

    // causal MFMA attention (balanced complementary strips)
    attn_mfma6<<<dim3(512), 256, 0, stream>>>(qkvb, Kp, Vtp, headsb);

    // output projection
    gemm_nt_lds<float><<<dim3(BB * SS / 128, DD / 128), 256, 0, stream>>>(
        headsb, wob, out, BB * SS, DD, DD);
}